// Round 8
// baseline (2318.017 us; speedup 1.0000x reference)
//
#include <hip/hip_runtime.h>

// ---------------- problem constants ----------------
constexpr int D0  = 11;
constexpr int Hh  = 200;
constexpr int Ww  = 176;
constexpr int HWC = Hh * Ww;        // 35200
constexpr int NV  = 16000;          // % 64 == 0
constexpr int ND1 = 5;
constexpr int ND2 = 2;
constexpr int CAPN = 32000;         // n1,n2 <= 2*NV
constexpr float EPS = 1e-5f;

// padded counter slots: each counter on its own 128B line
#define PC(i) ((i) << 5)
// slot map: 0:n1 1:n2 | 2+k (k<27): conv1 | 29+k (k<3): conv2
//           32+k (k<27): conv34 | 59+k (k<3): conv5

// ---------------- two-level grid barrier ----------------
struct GBar {                       // 4352 B, all counters line-padded
    int grp[16 * 32];               // per-group arrival counters (64 blocks/group)
    int gflag[16 * 32];             // per-group release flags
    int root[32];                   // root arrival counter
    int rflag[32];                  // root release flag
};
constexpr int NBAR = 16;

__device__ inline void gsync(GBar* B, int nb) {
    __threadfence();
    __syncthreads();
    if (threadIdx.x == 0) {
        const int b = (int)blockIdx.x;
        const int g = b >> 6;
        const int ngrp = (nb + 63) >> 6;
        int gsz = nb - (g << 6); if (gsz > 64) gsz = 64;
        int prev = atomicAdd(&B->grp[g << 5], 1);
        if (prev == gsz - 1) {
            int p2 = atomicAdd(&B->root[0], 1);
            if (p2 == ngrp - 1) {
                __hip_atomic_store(&B->rflag[0], 1, __ATOMIC_RELEASE, __HIP_MEMORY_SCOPE_AGENT);
            } else {
                while (!__hip_atomic_load(&B->rflag[0], __ATOMIC_ACQUIRE, __HIP_MEMORY_SCOPE_AGENT))
                    __builtin_amdgcn_s_sleep(2);
            }
            __hip_atomic_store(&B->gflag[g << 5], 1, __ATOMIC_RELEASE, __HIP_MEMORY_SCOPE_AGENT);
        } else {
            while (!__hip_atomic_load(&B->gflag[g << 5], __ATOMIC_ACQUIRE, __HIP_MEMORY_SCOPE_AGENT))
                __builtin_amdgcn_s_sleep(2);
        }
    }
    __syncthreads();
    __threadfence();
}

struct FuseP {
    const float *vf, *w1, *w2, *w3, *w4, *w5, *bg, *bb, *bm, *bv;
    const int* coors;
    float* out;
    int* ctr;
    GBar* bars;
    float *acc1, *accX, *acc5;
    int *grid0, *grid1, *list1, *list2;
    float *w1t, *w2t, *w3t, *w4t, *w5t;
    float *fA, *fB;
    int2 *pairs1, *pairs2, *pairs34, *pairs5;
    int out_n4;
};

// ---------------- wave/block-aggregated helpers ----------------
__device__ inline int wave_append(bool has, int* counter) {
    unsigned long long m = __ballot(has);
    if (!m) return -1;
    int lane = threadIdx.x & 63;
    int leader = __builtin_ctzll(m);
    int base = 0;
    if (lane == leader) base = atomicAdd(counter, (int)__popcll(m));
    base = __shfl(base, leader);
    return has ? base + (int)__popcll(m & ((1ull << lane) - 1)) : -1;
}

__device__ inline int block_append(bool has, int* counter, int* lds) {
    int tid = threadIdx.x;
    int w = tid >> 6, lane = tid & 63;
    unsigned long long m = __ballot(has);
    if (lane == 0) lds[w] = (int)__popcll(m);
    __syncthreads();
    if (tid == 0) {
        int t0 = lds[0], t1 = lds[1], t2 = lds[2], t3 = lds[3];
        int base = atomicAdd(counter, t0 + t1 + t2 + t3);
        lds[4] = base;
        lds[5] = base + t0;
        lds[6] = base + t0 + t1;
        lds[7] = base + t0 + t1 + t2;
    }
    __syncthreads();
    int base = lds[4 + w];
    return has ? base + (int)__popcll(m & ((1ull << lane) - 1)) : -1;
}

// ---------------- pair-batched sparse conv core ----------------
template<int XS, bool HALF, int NT, int STRIDE>
__device__ void pconv_core(const float* __restrict__ fin, const float* __restrict__ wt,
    const int2* __restrict__ pairs, const int* __restrict__ cnt,
    float* __restrict__ acc, int lane, int wid, int nwave) {
    int sum = 0;
    #pragma unroll
    for (int k = 0; k < NT; ++k) sum += cnt[k << 5];
    const int total = HALF ? 2 * sum : sum;
    int chunk = (total + nwave - 1) / nwave;
    int v = wid * chunk;
    int v1 = v + chunk; if (v1 > total) v1 = total;
    if (v < v1) {
        int s = 0, soff = 0;
        int send = cnt[0];
        while (v >= send) { soff = send; ++s; send += cnt[(HALF ? (s >> 1) : s) << 5]; }
        float w[64];
        int xofs = 0;
        const int2* pb = nullptr;
        bool need = true;
        while (v < v1) {
            while (v >= send) { soff = send; ++s; send += cnt[(HALF ? (s >> 1) : s) << 5]; need = true; }
            if (need) {
                const float* wp = wt + (size_t)s * 4096 + lane;
                #pragma unroll
                for (int c = 0; c < 64; ++c) w[c] = wp[(size_t)c * 64];
                if (HALF) xofs = (s & 1) * 64;
                pb = pairs + (size_t)(HALF ? (s >> 1) : s) * STRIDE - soff;
                need = false;
            }
            int e = v1 < send ? v1 : send;
            for (; v + 1 < e; v += 2) {
                int2 prA = pb[v];
                int2 prB = pb[v + 1];
                int ja = __builtin_amdgcn_readfirstlane(prA.x);
                int ya = __builtin_amdgcn_readfirstlane(prA.y);
                int jb = __builtin_amdgcn_readfirstlane(prB.x);
                int yb = __builtin_amdgcn_readfirstlane(prB.y);
                const float* xa = fin + (size_t)ja * XS + xofs;
                const float* xb = fin + (size_t)jb * XS + xofs;
                float a0=0.f,a1=0.f,a2=0.f,a3=0.f,b0=0.f,b1=0.f,b2=0.f,b3=0.f;
                #pragma unroll
                for (int c = 0; c < 64; c += 4) {
                    a0 = fmaf(xa[c],     w[c],     a0);
                    a1 = fmaf(xa[c + 1], w[c + 1], a1);
                    a2 = fmaf(xa[c + 2], w[c + 2], a2);
                    a3 = fmaf(xa[c + 3], w[c + 3], a3);
                    b0 = fmaf(xb[c],     w[c],     b0);
                    b1 = fmaf(xb[c + 1], w[c + 1], b1);
                    b2 = fmaf(xb[c + 2], w[c + 2], b2);
                    b3 = fmaf(xb[c + 3], w[c + 3], b3);
                }
                unsafeAtomicAdd(acc + ((size_t)ya << 6) + lane, (a0 + a1) + (a2 + a3));
                unsafeAtomicAdd(acc + ((size_t)yb << 6) + lane, (b0 + b1) + (b2 + b3));
            }
            if (v < e) {
                int2 pr = pb[v]; ++v;
                int jp = __builtin_amdgcn_readfirstlane(pr.x);
                int yp = __builtin_amdgcn_readfirstlane(pr.y);
                const float* xp = fin + (size_t)jp * XS + xofs;
                float a0=0.f,a1=0.f,a2=0.f,a3=0.f;
                #pragma unroll
                for (int c = 0; c < 64; c += 4) {
                    a0 = fmaf(xp[c],     w[c],     a0);
                    a1 = fmaf(xp[c + 1], w[c + 1], a1);
                    a2 = fmaf(xp[c + 2], w[c + 2], a2);
                    a3 = fmaf(xp[c + 3], w[c + 3], a3);
                }
                unsafeAtomicAdd(acc + ((size_t)yp << 6) + lane, (a0 + a1) + (a2 + a3));
            }
        }
    }
}

// ---------------- BN + ReLU core ----------------
template<bool ZERO>
__device__ void bn_core(float* __restrict__ acc, float* __restrict__ f, int n,
    const float* __restrict__ bg, const float* __restrict__ bb,
    const float* __restrict__ bm, const float* __restrict__ bv,
    int gtid, int stride) {
    for (int idx = gtid; idx < n * 64; idx += stride) {
        int o = idx & 63;
        float sc = bg[o] / sqrtf(bv[o] + EPS);
        float sh = bb[o] - bm[o] * sc;
        f[idx] = fmaxf(fmaf(acc[idx], sc, sh), 0.f);
        if (ZERO) acc[idx] = 0.f;
    }
}

// ---------------- the fused persistent kernel ----------------
__global__ __launch_bounds__(256, 4) void fused_k(FuseP P) {
    __shared__ int   lds8[8];
    __shared__ float tile[64 * 65];
    __shared__ int   pp[64];

    const int tid  = threadIdx.x;
    const int bid  = (int)blockIdx.x;
    const int nb   = (int)gridDim.x;
    const int gt   = nb * 256;
    const int nwv  = gt >> 6;
    const int gtid = bid * 256 + tid;
    const int lane = tid & 63;
    const int wid  = gtid >> 6;

    int bi = 0;
    auto SYNC = [&]() { gsync(&P.bars[bi], nb); ++bi; };

    // ---- P1: scatter coors into grid0 + weight transposes ----
    // (ctr/bars zeroed and grid0/grid1 filled with -1 by host memsets)
    for (int i = gtid; i < NV; i += gt) {
        int4 c = reinterpret_cast<const int4*>(P.coors)[i];
        P.grid0[c.y * HWC + c.z * Ww + c.w] = i;
    }
    for (int idx = gtid; idx < 466944; idx += gt) {
        const float* src; float* dst; int I, K, local;
        if (idx < 221184)      { src = P.w1; dst = P.w1t; I = 128; K = 27; local = idx; }
        else if (idx < 233472) { src = P.w2; dst = P.w2t; I = 64;  K = 3;  local = idx - 221184; }
        else if (idx < 344064) { src = P.w3; dst = P.w3t; I = 64;  K = 27; local = idx - 233472; }
        else if (idx < 454656) { src = P.w4; dst = P.w4t; I = 64;  K = 27; local = idx - 344064; }
        else                   { src = P.w5; dst = P.w5t; I = 64;  K = 3;  local = idx - 454656; }
        int o = local / (I * K), r = local % (I * K), ii = r / K, k = r % K;
        dst[(k * I + ii) * 64 + o] = src[local];   // wt[k][i][o]
    }
    SYNC();

    // ---- P2: list1/grid1, list2, conv1 pair fill, zero acc1/accX ----
    for (int base = 0; base < ND1 * HWC; base += gt) {
        int p = base + gtid;
        bool occ = false;
        if (p < ND1 * HWC) {
            int d1 = p / HWC, yx = p - d1 * HWC;
            int b = (2 * d1) * HWC + yx;
            occ = (P.grid0[b] >= 0) || (P.grid0[b + HWC] >= 0) || (P.grid0[b + 2 * HWC] >= 0);
        }
        int s = block_append(occ, P.ctr + PC(0), lds8);
        if (occ) { P.grid1[p] = s; P.list1[s] = p; }
    }
    for (int base = 0; base < ND2 * HWC; base += gt) {
        int p = base + gtid;
        bool occ = false;
        if (p < ND2 * HWC) {
            int d2 = p / HWC, yx = p - d2 * HWC;
            #pragma unroll
            for (int dd = 0; dd < 7; ++dd) occ |= (P.grid0[(4 * d2 + dd) * HWC + yx] >= 0);
        }
        int s = block_append(occ, P.ctr + PC(1), lds8);
        if (occ) P.list2[s] = p;
    }
    for (int idx = gtid; idx < 27 * NV; idx += gt) {   // conv1 fill (k wave-uniform)
        int k = idx / NV, i = idx - k * NV;
        int4 c = reinterpret_cast<const int4*>(P.coors)[i];
        int kd = k / 9, r = k % 9, kh = r / 3, kw = r % 3;
        int zz = c.y + kd - 1, yy = c.z + kh - 1, xx = c.w + kw - 1;
        int j = -1; bool has = false;
        if ((unsigned)zz < (unsigned)D0 && (unsigned)yy < (unsigned)Hh &&
            (unsigned)xx < (unsigned)Ww) {
            j = P.grid0[zz * HWC + yy * Ww + xx];
            has = j >= 0;
        }
        int rel = wave_append(has, P.ctr + PC(2 + k));
        if (has) { int2 pr; pr.x = j; pr.y = i; P.pairs1[k * NV + rel] = pr; }
    }
    {
        float4 z4 = make_float4(0.f, 0.f, 0.f, 0.f);
        float4* a1 = (float4*)P.acc1;
        for (int i = gtid; i < NV * 16; i += gt) a1[i] = z4;
        float4* aX = (float4*)P.accX;
        for (int i = gtid; i < CAPN * 16; i += gt) aX[i] = z4;
    }
    SYNC();

    // ---- P3: conv2/conv34/conv5 pair fills, zero acc5/out ----
    const int n1 = P.ctr[PC(0)];
    const int n2 = P.ctr[PC(1)];
    for (int idx = gtid; idx < 3 * CAPN; idx += gt) {      // conv2
        int k = idx / CAPN, s1 = idx - k * CAPN;
        bool has = false; int j = -1;
        if (s1 < n1) {
            int p = P.list1[s1]; int d1 = p / HWC, yx = p - d1 * HWC;
            j = P.grid0[(2 * d1 + k) * HWC + yx];
            has = j >= 0;
        }
        int rel = wave_append(has, P.ctr + PC(29 + k));
        if (has) { int2 pr; pr.x = j; pr.y = s1; P.pairs2[k * CAPN + rel] = pr; }
    }
    for (int idx = gtid; idx < 27 * CAPN; idx += gt) {     // conv3/4
        int k = idx / CAPN, s1 = idx - k * CAPN;
        bool has = false; int j = -1;
        if (s1 < n1) {
            int p = P.list1[s1];
            int d1 = p / HWC, yx = p - d1 * HWC, y = yx / Ww, x = yx - y * Ww;
            int kd = k / 9, r = k % 9, kh = r / 3, kw = r % 3;
            int dd = d1 + kd - 1, yy = y + kh - 1, xx = x + kw - 1;
            if ((unsigned)dd < (unsigned)ND1 && (unsigned)yy < (unsigned)Hh &&
                (unsigned)xx < (unsigned)Ww) {
                j = P.grid1[dd * HWC + yy * Ww + xx];
                has = j >= 0;
            }
        }
        int rel = wave_append(has, P.ctr + PC(32 + k));
        if (has) { int2 pr; pr.x = j; pr.y = s1; P.pairs34[k * CAPN + rel] = pr; }
    }
    for (int idx = gtid; idx < 3 * CAPN; idx += gt) {      // conv5
        int k = idx / CAPN, s2 = idx - k * CAPN;
        bool has = false; int j = -1;
        if (s2 < n2) {
            int p = P.list2[s2]; int d2 = p / HWC, yx = p - d2 * HWC;
            j = P.grid1[(2 * d2 + k) * HWC + yx];
            has = j >= 0;
        }
        int rel = wave_append(has, P.ctr + PC(59 + k));
        if (has) { int2 pr; pr.x = j; pr.y = s2; P.pairs5[k * CAPN + rel] = pr; }
    }
    {
        float4 z4 = make_float4(0.f, 0.f, 0.f, 0.f);
        float4* a5 = (float4*)P.acc5;
        for (int i = gtid; i < CAPN * 16; i += gt) a5[i] = z4;
        float4* o4 = (float4*)P.out;
        for (int i = gtid; i < P.out_n4; i += gt) o4[i] = z4;
    }
    SYNC();

    // ---- conv/bn chain ----
    pconv_core<128, true, 27, NV>(P.vf, P.w1t, P.pairs1, P.ctr + PC(2), P.acc1, lane, wid, nwv);
    SYNC();
    bn_core<false>(P.acc1, P.fA, NV, P.bg, P.bb, P.bm, P.bv, gtid, gt);
    SYNC();
    pconv_core<64, false, 3, CAPN>(P.fA, P.w2t, P.pairs2, P.ctr + PC(29), P.accX, lane, wid, nwv);
    SYNC();
    bn_core<true>(P.accX, P.fB, n1, P.bg + 64, P.bb + 64, P.bm + 64, P.bv + 64, gtid, gt);
    SYNC();
    pconv_core<64, false, 27, CAPN>(P.fB, P.w3t, P.pairs34, P.ctr + PC(32), P.accX, lane, wid, nwv);
    SYNC();
    bn_core<true>(P.accX, P.fB, n1, P.bg + 128, P.bb + 128, P.bm + 128, P.bv + 128, gtid, gt);
    SYNC();
    pconv_core<64, false, 27, CAPN>(P.fB, P.w4t, P.pairs34, P.ctr + PC(32), P.accX, lane, wid, nwv);
    SYNC();
    bn_core<false>(P.accX, P.fB, n1, P.bg + 192, P.bb + 192, P.bm + 192, P.bv + 192, gtid, gt);
    SYNC();
    pconv_core<64, false, 3, CAPN>(P.fB, P.w5t, P.pairs5, P.ctr + PC(59), P.acc5, lane, wid, nwv);
    SYNC();

    // ---- P13: final BN + ReLU + transpose-scatter ----
    for (int t = bid; t < CAPN / 64; t += nb) {
        int sb = t * 64;
        if (tid < 64) pp[tid] = (sb + tid < n2) ? P.list2[sb + tid] : -1;
        int o = tid & 63;
        float sc = P.bg[256 + o] / sqrtf(P.bv[256 + o] + EPS);
        float sh = P.bb[256 + o] - P.bm[256 + o] * sc;
        __syncthreads();
        #pragma unroll
        for (int it = 0; it < 16; ++it) {
            int sl = it * 4 + (tid >> 6);
            int s2 = sb + sl;
            if (s2 < n2)
                tile[sl * 65 + o] = fmaxf(fmaf(P.acc5[(size_t)s2 * 64 + o], sc, sh), 0.f);
        }
        __syncthreads();
        #pragma unroll
        for (int it = 0; it < 16; ++it) {
            int og = it * 4 + (tid >> 6);
            int sl = tid & 63;
            int p = pp[sl];
            if (p >= 0) {
                int d2 = p / HWC, yx = p - d2 * HWC;
                P.out[(size_t)(og * ND2 + d2) * HWC + yx] = tile[sl * 65 + og];
            }
        }
        __syncthreads();
    }
}

// ================= fallback multi-kernel path (R6, proven) =================
__global__ __launch_bounds__(256) void setup1_k(const int* __restrict__ coors,
    int* __restrict__ grid0,
    const float* __restrict__ w1, const float* __restrict__ w2,
    const float* __restrict__ w3, const float* __restrict__ w4,
    const float* __restrict__ w5,
    float* __restrict__ w1t, float* __restrict__ w2t, float* __restrict__ w3t,
    float* __restrict__ w4t, float* __restrict__ w5t) {
    int idx = blockIdx.x * 256 + threadIdx.x;
    int role = blockIdx.y;
    if (role == 0) {
        if (idx < NV) {
            int4 c = reinterpret_cast<const int4*>(coors)[idx];
            grid0[c.y * HWC + c.z * Ww + c.w] = idx;
        }
        return;
    }
    const float* src; float* dst; int I, K;
    switch (role) {
        case 1:  src = w1; dst = w1t; I = 128; K = 27; break;
        case 2:  src = w2; dst = w2t; I = 64;  K = 3;  break;
        case 3:  src = w3; dst = w3t; I = 64;  K = 27; break;
        case 4:  src = w4; dst = w4t; I = 64;  K = 27; break;
        default: src = w5; dst = w5t; I = 64;  K = 3;  break;
    }
    int tot = 64 * I * K;
    if (idx >= tot) return;
    int o = idx / (I * K), r = idx % (I * K), ii = r / K, k = r % K;
    dst[(k * I + ii) * 64 + o] = src[idx];
}

__global__ __launch_bounds__(256) void setup2_k(const int* __restrict__ coors,
    const int* __restrict__ grid0, int* __restrict__ grid1,
    int* __restrict__ list1, int* __restrict__ list2, int* __restrict__ ctr,
    int2* __restrict__ pairs1) {
    __shared__ int lds[8];
    int bid = blockIdx.x, tid = threadIdx.x;
    if (bid < 688) {
        int p = bid * 256 + tid;
        bool occ = false;
        if (p < ND1 * HWC) {
            int d1 = p / HWC, yx = p - d1 * HWC;
            int b = (2 * d1) * HWC + yx;
            occ = (grid0[b] >= 0) || (grid0[b + HWC] >= 0) || (grid0[b + 2 * HWC] >= 0);
        }
        int s = block_append(occ, ctr + PC(0), lds);
        if (occ) { grid1[p] = s; list1[s] = p; }
    } else if (bid < 963) {
        int p = (bid - 688) * 256 + tid;
        bool occ = false;
        if (p < ND2 * HWC) {
            int d2 = p / HWC, yx = p - d2 * HWC;
            #pragma unroll
            for (int dd = 0; dd < 7; ++dd) occ |= (grid0[(4 * d2 + dd) * HWC + yx] >= 0);
        }
        int s = block_append(occ, ctr + PC(1), lds);
        if (occ) list2[s] = p;
    } else {
        int idx = (bid - 963) * 256 + tid;
        int k = idx / NV;
        bool has = false; int j = -1;
        int i = idx - k * NV;
        if (idx < 27 * NV) {
            int4 c = reinterpret_cast<const int4*>(coors)[i];
            int kd = k / 9, r = k % 9, kh = r / 3, kw = r % 3;
            int zz = c.y + kd - 1, yy = c.z + kh - 1, xx = c.w + kw - 1;
            if ((unsigned)zz < (unsigned)D0 && (unsigned)yy < (unsigned)Hh &&
                (unsigned)xx < (unsigned)Ww) {
                j = grid0[zz * HWC + yy * Ww + xx];
                has = j >= 0;
            }
        }
        int rel = wave_append(has, ctr + PC(2 + k));
        if (has) { int2 pr; pr.x = j; pr.y = i; pairs1[k * NV + rel] = pr; }
    }
}

__global__ __launch_bounds__(256) void setup3_k(const int* __restrict__ grid0,
    const int* __restrict__ grid1, const int* __restrict__ list1,
    const int* __restrict__ list2, int* __restrict__ ctr,
    int2* __restrict__ pairs2, int2* __restrict__ pairs34,
    int2* __restrict__ pairs5) {
    int bid = blockIdx.x, tid = threadIdx.x;
    int n1 = ctr[PC(0)], n2 = ctr[PC(1)];
    if (bid < 375) {
        int idx = bid * 256 + tid;
        int k = idx / CAPN, s1 = idx - k * CAPN;
        bool has = false; int j = -1;
        if (s1 < n1) {
            int p = list1[s1]; int d1 = p / HWC, yx = p - d1 * HWC;
            j = grid0[(2 * d1 + k) * HWC + yx];
            has = j >= 0;
        }
        int rel = wave_append(has, ctr + PC(29 + k));
        if (has) { int2 pr; pr.x = j; pr.y = s1; pairs2[k * CAPN + rel] = pr; }
    } else if (bid < 3750) {
        int idx = (bid - 375) * 256 + tid;
        int k = idx / CAPN, s1 = idx - k * CAPN;
        bool has = false; int j = -1;
        if (s1 < n1) {
            int p = list1[s1];
            int d1 = p / HWC, yx = p - d1 * HWC, y = yx / Ww, x = yx - y * Ww;
            int kd = k / 9, r = k % 9, kh = r / 3, kw = r % 3;
            int dd = d1 + kd - 1, yy = y + kh - 1, xx = x + kw - 1;
            if ((unsigned)dd < (unsigned)ND1 && (unsigned)yy < (unsigned)Hh &&
                (unsigned)xx < (unsigned)Ww) {
                j = grid1[dd * HWC + yy * Ww + xx];
                has = j >= 0;
            }
        }
        int rel = wave_append(has, ctr + PC(32 + k));
        if (has) { int2 pr; pr.x = j; pr.y = s1; pairs34[k * CAPN + rel] = pr; }
    } else {
        int idx = (bid - 3750) * 256 + tid;
        int k = idx / CAPN, s2 = idx - k * CAPN;
        bool has = false; int j = -1;
        if (s2 < n2) {
            int p = list2[s2]; int d2 = p / HWC, yx = p - d2 * HWC;
            j = grid1[(2 * d2 + k) * HWC + yx];
            has = j >= 0;
        }
        int rel = wave_append(has, ctr + PC(59 + k));
        if (has) { int2 pr; pr.x = j; pr.y = s2; pairs5[k * CAPN + rel] = pr; }
    }
}

template<int XS, bool HALF, int NT, int STRIDE>
__global__ __launch_bounds__(256, 4) void pconv_k(
    const float* __restrict__ fin, const float* __restrict__ wt,
    const int2* __restrict__ pairs, const int* __restrict__ cnt,
    float* __restrict__ acc) {
    pconv_core<XS, HALF, NT, STRIDE>(fin, wt, pairs, cnt, acc,
        threadIdx.x & 63,
        (int)blockIdx.x * 4 + ((int)threadIdx.x >> 6),
        (int)gridDim.x * 4);
}

template<bool ZERO, bool FIXEDN>
__global__ __launch_bounds__(256) void bn_k(float* __restrict__ acc,
    float* __restrict__ f, const int* __restrict__ ctr,
    const float* __restrict__ bg, const float* __restrict__ bb,
    const float* __restrict__ bm, const float* __restrict__ bv) {
    int n = FIXEDN ? NV : ctr[PC(0)];
    bn_core<ZERO>(acc, f, n, bg, bb, bm, bv,
        (int)blockIdx.x * 256 + threadIdx.x, (int)gridDim.x * 256);
}

__global__ __launch_bounds__(256) void bn5_k(const float* __restrict__ acc5,
    const int* __restrict__ list2, const int* __restrict__ ctr,
    const float* __restrict__ bg, const float* __restrict__ bb,
    const float* __restrict__ bm, const float* __restrict__ bv,
    float* __restrict__ out) {
    __shared__ float tile[64 * 65];
    __shared__ int pp[64];
    int n2 = ctr[PC(1)];
    int sb = blockIdx.x * 64;
    int tid = threadIdx.x;
    if (tid < 64) pp[tid] = (sb + tid < n2) ? list2[sb + tid] : -1;
    int o = tid & 63;
    float sc = bg[o] / sqrtf(bv[o] + EPS);
    float sh = bb[o] - bm[o] * sc;
    __syncthreads();
    #pragma unroll
    for (int it = 0; it < 16; ++it) {
        int sl = it * 4 + (tid >> 6);
        int s2 = sb + sl;
        if (s2 < n2)
            tile[sl * 65 + o] = fmaxf(fmaf(acc5[(size_t)s2 * 64 + o], sc, sh), 0.f);
    }
    __syncthreads();
    #pragma unroll
    for (int it = 0; it < 16; ++it) {
        int og = it * 4 + (tid >> 6);
        int sl = tid & 63;
        int p = pp[sl];
        if (p >= 0) {
            int d2 = p / HWC, yx = p - d2 * HWC;
            out[(size_t)(og * ND2 + d2) * HWC + yx] = tile[sl * 65 + og];
        }
    }
}

// ---------------- launch ----------------
extern "C" void kernel_launch(void* const* d_in, const int* in_sizes, int n_in,
                              void* d_out, int out_size, void* d_ws, size_t ws_size,
                              hipStream_t stream) {
    char* ws = (char*)d_ws;
    size_t off = 0;
    auto take = [&](size_t n) -> void* {
        void* pp = ws + off;
        off += (n + 255) & ~(size_t)255;
        return pp;
    };

    FuseP P;
    P.vf = (const float*)d_in[0];
    P.w1 = (const float*)d_in[1];
    P.w2 = (const float*)d_in[2];
    P.w3 = (const float*)d_in[3];
    P.w4 = (const float*)d_in[4];
    P.w5 = (const float*)d_in[5];
    P.bg = (const float*)d_in[6];
    P.bb = (const float*)d_in[7];
    P.bm = (const float*)d_in[8];
    P.bv = (const float*)d_in[9];
    P.coors = (const int*)d_in[10];
    P.out = (float*)d_out;
    P.out_n4 = out_size / 4;

    P.ctr   = (int*)take(16384);
    P.bars  = (GBar*)take(NBAR * sizeof(GBar));   // adjacent to ctr
    P.acc1  = (float*)take((size_t)NV * 64 * 4);
    P.accX  = (float*)take((size_t)CAPN * 64 * 4);
    P.acc5  = (float*)take((size_t)CAPN * 64 * 4);
    size_t zero_all = (char*)P.acc5 + (size_t)CAPN * 64 * 4 - (char*)P.ctr;
    P.grid0 = (int*)take((size_t)D0 * HWC * 4);
    P.grid1 = (int*)take((size_t)ND1 * HWC * 4);
    size_t ff_len = (char*)P.grid1 + (size_t)ND1 * HWC * 4 - (char*)P.grid0;
    P.list1 = (int*)take(CAPN * 4);
    P.list2 = (int*)take(CAPN * 4);
    P.w1t   = (float*)take((size_t)27 * 128 * 64 * 4);
    P.w2t   = (float*)take((size_t)3 * 64 * 64 * 4);
    P.w3t   = (float*)take((size_t)27 * 64 * 64 * 4);
    P.w4t   = (float*)take((size_t)27 * 64 * 64 * 4);
    P.w5t   = (float*)take((size_t)3 * 64 * 64 * 4);
    P.fA    = (float*)take((size_t)NV * 64 * 4);
    P.fB    = (float*)take((size_t)CAPN * 64 * 4);
    P.pairs1  = (int2*)take((size_t)27 * NV * 8);
    P.pairs2  = (int2*)take((size_t)3 * CAPN * 8);
    P.pairs34 = (int2*)take((size_t)27 * CAPN * 8);
    P.pairs5  = (int2*)take((size_t)3 * CAPN * 8);

    // host-only queries (deterministic, capture-safe): co-residency capacity
    int nb = 0;
    {
        int dev = 0;
        if (hipGetDevice(&dev) == hipSuccess) {
            int ncu = 0, maxb = 0;
            hipDeviceGetAttribute(&ncu, hipDeviceAttributeMultiprocessorCount, dev);
            hipError_t oe = hipOccupancyMaxActiveBlocksPerMultiprocessor(
                &maxb, (const void*)fused_k, 256, 0);
            if (oe == hipSuccess && ncu > 0 && maxb > 0) {
                nb = maxb * ncu;
                if (nb > 1024) nb = 1024;
            }
        }
    }

    if (nb >= 128) {
        // fused path: one persistent kernel, hand-rolled grid barrier
        size_t bar_len = 16384 + (size_t)NBAR * sizeof(GBar);
        hipMemsetAsync(P.ctr, 0x00, bar_len, stream);          // ctr + barrier state
        hipMemsetAsync(P.grid0, 0xFF, ff_len, stream);         // grid0/grid1 = -1
        fused_k<<<nb, 256, 0, stream>>>(P);
    } else {
        // fallback path (R6 multi-kernel, proven)
        hipMemsetAsync(P.ctr, 0x00, zero_all, stream);
        hipMemsetAsync(P.grid0, 0xFF, ff_len, stream);
        hipMemsetAsync(P.out, 0x00, (size_t)out_size * 4, stream);

        setup1_k<<<dim3(864, 6), 256, 0, stream>>>(P.coors, P.grid0,
            P.w1, P.w2, P.w3, P.w4, P.w5, P.w1t, P.w2t, P.w3t, P.w4t, P.w5t);
        setup2_k<<<2651, 256, 0, stream>>>(P.coors, P.grid0, P.grid1,
            P.list1, P.list2, P.ctr, P.pairs1);
        setup3_k<<<4125, 256, 0, stream>>>(P.grid0, P.grid1, P.list1, P.list2,
            P.ctr, P.pairs2, P.pairs34, P.pairs5);

        pconv_k<128, true, 27, NV><<<1024, 256, 0, stream>>>(P.vf, P.w1t, P.pairs1,
            P.ctr + PC(2), P.acc1);
        bn_k<false, true><<<(NV * 64) / 256, 256, 0, stream>>>(P.acc1, P.fA, P.ctr,
            P.bg, P.bb, P.bm, P.bv);
        pconv_k<64, false, 3, CAPN><<<1024, 256, 0, stream>>>(P.fA, P.w2t, P.pairs2,
            P.ctr + PC(29), P.accX);
        bn_k<true, false><<<(CAPN * 64) / 256, 256, 0, stream>>>(P.accX, P.fB, P.ctr,
            P.bg + 64, P.bb + 64, P.bm + 64, P.bv + 64);
        pconv_k<64, false, 27, CAPN><<<1024, 256, 0, stream>>>(P.fB, P.w3t, P.pairs34,
            P.ctr + PC(32), P.accX);
        bn_k<true, false><<<(CAPN * 64) / 256, 256, 0, stream>>>(P.accX, P.fB, P.ctr,
            P.bg + 128, P.bb + 128, P.bm + 128, P.bv + 128);
        pconv_k<64, false, 27, CAPN><<<1024, 256, 0, stream>>>(P.fB, P.w4t, P.pairs34,
            P.ctr + PC(32), P.accX);
        bn_k<false, false><<<(CAPN * 64) / 256, 256, 0, stream>>>(P.accX, P.fB, P.ctr,
            P.bg + 192, P.bb + 192, P.bm + 192, P.bv + 192);
        pconv_k<64, false, 3, CAPN><<<1024, 256, 0, stream>>>(P.fB, P.w5t, P.pairs5,
            P.ctr + PC(59), P.acc5);
        bn5_k<<<CAPN / 64, 256, 0, stream>>>(P.acc5, P.list2, P.ctr,
            P.bg + 256, P.bb + 256, P.bm + 256, P.bv + 256, P.out);
    }
}

// Round 9
// 435.545 us; speedup vs baseline: 5.3221x; 5.3221x over previous
//
#include <hip/hip_runtime.h>

// ---------------- problem constants ----------------
constexpr int D0  = 11;
constexpr int Hh  = 200;
constexpr int Ww  = 176;
constexpr int HWC = Hh * Ww;        // 35200
constexpr int NV  = 16000;          // % 64 == 0
constexpr int ND1 = 5;
constexpr int ND2 = 2;
constexpr int CAPN = 32000;         // n1,n2 <= 2*NV
constexpr float EPS = 1e-5f;

// padded counter slots: each counter on its own 128B line
#define PC(i) ((i) << 5)
// slot map: 0:n1 1:n2 | 2+k (k<27): conv1 | 29+k (k<3): conv2
//           32+k (k<27): conv34 | 59+k (k<3): conv5

// ---------------- wave/block-aggregated helpers ----------------
__device__ inline int wave_append(bool has, int* counter) {
    unsigned long long m = __ballot(has);
    if (!m) return -1;
    int lane = threadIdx.x & 63;
    int leader = __builtin_ctzll(m);
    int base = 0;
    if (lane == leader) base = atomicAdd(counter, (int)__popcll(m));
    base = __shfl(base, leader);
    return has ? base + (int)__popcll(m & ((1ull << lane) - 1)) : -1;
}

__device__ inline int block_append(bool has, int* counter, int* lds) {
    int tid = threadIdx.x;
    int w = tid >> 6, lane = tid & 63;
    unsigned long long m = __ballot(has);
    if (lane == 0) lds[w] = (int)__popcll(m);
    __syncthreads();
    if (tid == 0) {
        int t0 = lds[0], t1 = lds[1], t2 = lds[2], t3 = lds[3];
        int base = atomicAdd(counter, t0 + t1 + t2 + t3);
        lds[4] = base;
        lds[5] = base + t0;
        lds[6] = base + t0 + t1;
        lds[7] = base + t0 + t1 + t2;
    }
    __syncthreads();
    int base = lds[4 + w];
    return has ? base + (int)__popcll(m & ((1ull << lane) - 1)) : -1;
}

// ---------------- setup 1: scatter coors + weight transposes ----------------
__global__ __launch_bounds__(256) void setup1_k(const int* __restrict__ coors,
    int* __restrict__ grid0,
    const float* __restrict__ w1, const float* __restrict__ w2,
    const float* __restrict__ w3, const float* __restrict__ w4,
    const float* __restrict__ w5,
    float* __restrict__ w1t, float* __restrict__ w2t, float* __restrict__ w3t,
    float* __restrict__ w4t, float* __restrict__ w5t) {
    int idx = blockIdx.x * 256 + threadIdx.x;
    int role = blockIdx.y;
    if (role == 0) {
        if (idx < NV) {
            int4 c = reinterpret_cast<const int4*>(coors)[idx];
            grid0[c.y * HWC + c.z * Ww + c.w] = idx;
        }
        return;
    }
    const float* src; float* dst; int I, K;
    switch (role) {
        case 1:  src = w1; dst = w1t; I = 128; K = 27; break;
        case 2:  src = w2; dst = w2t; I = 64;  K = 3;  break;
        case 3:  src = w3; dst = w3t; I = 64;  K = 27; break;
        case 4:  src = w4; dst = w4t; I = 64;  K = 27; break;
        default: src = w5; dst = w5t; I = 64;  K = 3;  break;
    }
    int tot = 64 * I * K;
    if (idx >= tot) return;
    int o = idx / (I * K), r = idx % (I * K), ii = r / K, k = r % K;
    dst[(k * I + ii) * 64 + o] = src[idx];   // wt[k][i][o]
}

// ---------------- setup 2: lists + conv1 pair fill ----------------
// flattened roles: [0,688) list1/grid1 | [688,963) list2/grid2 | [963,2651) conv1 fill
__global__ __launch_bounds__(256) void setup2_k(const int* __restrict__ coors,
    const int* __restrict__ grid0, int* __restrict__ grid1, int* __restrict__ grid2,
    int* __restrict__ list1, int* __restrict__ list2, int* __restrict__ ctr,
    int2* __restrict__ pairs1) {
    __shared__ int lds[8];
    int bid = blockIdx.x, tid = threadIdx.x;
    if (bid < 688) {
        int p = bid * 256 + tid;
        bool occ = false;
        if (p < ND1 * HWC) {
            int d1 = p / HWC, yx = p - d1 * HWC;
            int b = (2 * d1) * HWC + yx;
            occ = (grid0[b] >= 0) || (grid0[b + HWC] >= 0) || (grid0[b + 2 * HWC] >= 0);
        }
        int s = block_append(occ, ctr + PC(0), lds);
        if (occ) { grid1[p] = s; list1[s] = p; }
    } else if (bid < 963) {
        int p = (bid - 688) * 256 + tid;
        bool occ = false;
        if (p < ND2 * HWC) {
            int d2 = p / HWC, yx = p - d2 * HWC;
            #pragma unroll
            for (int dd = 0; dd < 7; ++dd) occ |= (grid0[(4 * d2 + dd) * HWC + yx] >= 0);
        }
        int s = block_append(occ, ctr + PC(1), lds);
        if (occ) { list2[s] = p; grid2[p] = s; }
    } else {
        int idx = (bid - 963) * 256 + tid;       // < 432128; 27*NV = 432000
        int k = idx / NV;                        // wave-uniform (NV % 64 == 0)
        bool has = false; int j = -1;
        int i = idx - k * NV;
        if (idx < 27 * NV) {
            int4 c = reinterpret_cast<const int4*>(coors)[i];
            int kd = k / 9, r = k % 9, kh = r / 3, kw = r % 3;
            int zz = c.y + kd - 1, yy = c.z + kh - 1, xx = c.w + kw - 1;
            if ((unsigned)zz < (unsigned)D0 && (unsigned)yy < (unsigned)Hh &&
                (unsigned)xx < (unsigned)Ww) {
                j = grid0[zz * HWC + yy * Ww + xx];
                has = j >= 0;
            }
        }
        int rel = wave_append(has, ctr + PC(2 + k));
        if (has) { int2 pr; pr.x = j; pr.y = i; pairs1[k * NV + rel] = pr; }
    }
}

// ---------------- setup 3: conv2 / conv34 / conv5 pair fills ----------------
// flattened roles: [0,375) conv2 | [375,3750) conv34 | [3750,4125) conv5
__global__ __launch_bounds__(256) void setup3_k(const int* __restrict__ grid0,
    const int* __restrict__ grid1, const int* __restrict__ list1,
    const int* __restrict__ list2, int* __restrict__ ctr,
    int2* __restrict__ pairs2, int2* __restrict__ pairs34,
    int2* __restrict__ pairs5) {
    int bid = blockIdx.x, tid = threadIdx.x;
    int n1 = ctr[PC(0)], n2 = ctr[PC(1)];
    if (bid < 375) {
        int idx = bid * 256 + tid;               // 3*CAPN exact
        int k = idx / CAPN, s1 = idx - k * CAPN; // k wave-uniform
        bool has = false; int j = -1;
        if (s1 < n1) {
            int p = list1[s1]; int d1 = p / HWC, yx = p - d1 * HWC;
            j = grid0[(2 * d1 + k) * HWC + yx];
            has = j >= 0;
        }
        int rel = wave_append(has, ctr + PC(29 + k));
        if (has) { int2 pr; pr.x = j; pr.y = s1; pairs2[k * CAPN + rel] = pr; }
    } else if (bid < 3750) {
        int idx = (bid - 375) * 256 + tid;       // 27*CAPN exact
        int k = idx / CAPN, s1 = idx - k * CAPN;
        bool has = false; int j = -1;
        if (s1 < n1) {
            int p = list1[s1];
            int d1 = p / HWC, yx = p - d1 * HWC, y = yx / Ww, x = yx - y * Ww;
            int kd = k / 9, r = k % 9, kh = r / 3, kw = r % 3;
            int dd = d1 + kd - 1, yy = y + kh - 1, xx = x + kw - 1;
            if ((unsigned)dd < (unsigned)ND1 && (unsigned)yy < (unsigned)Hh &&
                (unsigned)xx < (unsigned)Ww) {
                j = grid1[dd * HWC + yy * Ww + xx];
                has = j >= 0;
            }
        }
        int rel = wave_append(has, ctr + PC(32 + k));
        if (has) { int2 pr; pr.x = j; pr.y = s1; pairs34[k * CAPN + rel] = pr; }
    } else {
        int idx = (bid - 3750) * 256 + tid;      // 3*CAPN exact
        int k = idx / CAPN, s2 = idx - k * CAPN;
        bool has = false; int j = -1;
        if (s2 < n2) {
            int p = list2[s2]; int d2 = p / HWC, yx = p - d2 * HWC;
            j = grid1[(2 * d2 + k) * HWC + yx];
            has = j >= 0;
        }
        int rel = wave_append(has, ctr + PC(59 + k));
        if (has) { int2 pr; pr.x = j; pr.y = s2; pairs5[k * CAPN + rel] = pr; }
    }
}

// ---------------- quarter-split pair-batched sparse conv ----------------
// Each pair is processed by QN = XS/16 waves; wave qw owns input channels
// [16qw,16qw+16): only w[16] weight VGPRs (spill-proof at ANY register
// budget), 16 scalar x-loads per pair, one 256B fp32 atomic partial-sum.
// lane = output channel; slice = tap k; WS = per-tap weight stride.
template<int XS, int QN, int NT, int WS, int STRIDE>
__global__ __launch_bounds__(256, 4) void pconv_k(
    const float* __restrict__ fin, const float* __restrict__ wt,
    const int2* __restrict__ pairs, const int* __restrict__ cnt,
    float* __restrict__ acc) {
    const int lane = threadIdx.x & 63;
    const int wid = __builtin_amdgcn_readfirstlane(
        (int)blockIdx.x * 4 + ((int)threadIdx.x >> 6));
    const int nw = (int)gridDim.x * 4;
    const int qw  = wid & (QN - 1);
    const int rid = wid / QN;
    const int nr  = nw / QN;

    int total = 0;
    #pragma unroll
    for (int k = 0; k < NT; ++k) total += cnt[k << 5];

    int chunk = (total + nr - 1) / nr;
    int v = rid * chunk;
    int v1 = v + chunk; if (v1 > total) v1 = total;
    if (v >= v1) return;

    // walk to the slice containing v
    int s = 0, soff = 0;
    int send = cnt[0];
    while (v >= send) { soff = send; ++s; send += cnt[s << 5]; }

    float w[16];
    const int2* pb = nullptr;
    bool need = true;
    while (v < v1) {
        while (v >= send) { soff = send; ++s; send += cnt[s << 5]; need = true; }
        if (need) {
            const float* wp = wt + (size_t)s * WS + qw * 1024 + lane;
            #pragma unroll
            for (int c = 0; c < 16; ++c) w[c] = wp[(size_t)c * 64];
            pb = pairs + (size_t)s * STRIDE - soff;
            need = false;
        }
        int e = v1 < send ? v1 : send;
        // 2-pair unroll: two independent x-rows + FMA chains in flight
        for (; v + 1 < e; v += 2) {
            int2 prA = pb[v];
            int2 prB = pb[v + 1];
            int ja = __builtin_amdgcn_readfirstlane(prA.x);
            int ya = __builtin_amdgcn_readfirstlane(prA.y);
            int jb = __builtin_amdgcn_readfirstlane(prB.x);
            int yb = __builtin_amdgcn_readfirstlane(prB.y);
            const float* xa = fin + (size_t)ja * XS + qw * 16;
            const float* xb = fin + (size_t)jb * XS + qw * 16;
            float a0=0.f,a1=0.f,a2=0.f,a3=0.f,b0=0.f,b1=0.f,b2=0.f,b3=0.f;
            #pragma unroll
            for (int c = 0; c < 16; c += 4) {
                a0 = fmaf(xa[c],     w[c],     a0);
                a1 = fmaf(xa[c + 1], w[c + 1], a1);
                a2 = fmaf(xa[c + 2], w[c + 2], a2);
                a3 = fmaf(xa[c + 3], w[c + 3], a3);
                b0 = fmaf(xb[c],     w[c],     b0);
                b1 = fmaf(xb[c + 1], w[c + 1], b1);
                b2 = fmaf(xb[c + 2], w[c + 2], b2);
                b3 = fmaf(xb[c + 3], w[c + 3], b3);
            }
            unsafeAtomicAdd(acc + ((size_t)ya << 6) + lane, (a0 + a1) + (a2 + a3));
            unsafeAtomicAdd(acc + ((size_t)yb << 6) + lane, (b0 + b1) + (b2 + b3));
        }
        if (v < e) {
            int2 pr = pb[v]; ++v;
            int jp = __builtin_amdgcn_readfirstlane(pr.x);
            int yp = __builtin_amdgcn_readfirstlane(pr.y);
            const float* xp = fin + (size_t)jp * XS + qw * 16;
            float a0=0.f,a1=0.f,a2=0.f,a3=0.f;
            #pragma unroll
            for (int c = 0; c < 16; c += 4) {
                a0 = fmaf(xp[c],     w[c],     a0);
                a1 = fmaf(xp[c + 1], w[c + 1], a1);
                a2 = fmaf(xp[c + 2], w[c + 2], a2);
                a3 = fmaf(xp[c + 3], w[c + 3], a3);
            }
            unsafeAtomicAdd(acc + ((size_t)yp << 6) + lane, (a0 + a1) + (a2 + a3));
        }
    }
}

// ---------------- BN + ReLU (+ bounded accumulator re-zero) ----------------
template<bool ZERO, bool FIXEDN>
__global__ __launch_bounds__(256) void bn_k(float* __restrict__ acc,
    float* __restrict__ f, const int* __restrict__ ctr,
    const float* __restrict__ bg, const float* __restrict__ bb,
    const float* __restrict__ bm, const float* __restrict__ bv) {
    int idx = blockIdx.x * 256 + threadIdx.x;
    int site = idx >> 6, o = idx & 63;
    int n = FIXEDN ? NV : ctr[PC(0)];
    if (site < n) {
        float sc = bg[o] / sqrtf(bv[o] + EPS);
        float sh = bb[o] - bm[o] * sc;
        f[idx] = fmaxf(fmaf(acc[idx], sc, sh), 0.f);
        if (ZERO) acc[idx] = 0.f;
    }
}

// ---------------- final BN + ReLU + dense transpose write ----------------
// Writes the FULL dense output (zeros where unoccupied) -> no out memset.
__global__ __launch_bounds__(256) void bn5_k(const float* __restrict__ acc5,
    const int* __restrict__ grid2,
    const float* __restrict__ bg, const float* __restrict__ bb,
    const float* __restrict__ bm, const float* __restrict__ bv,
    float* __restrict__ out) {
    __shared__ float tile[64 * 65];
    __shared__ int pp[64];
    int sb = blockIdx.x * 64;              // 1100 blocks x 64 sites = 70400 exact
    int tid = threadIdx.x;
    if (tid < 64) pp[tid] = grid2[sb + tid];
    int o = tid & 63;
    float sc = bg[o] / sqrtf(bv[o] + EPS);
    float sh = bb[o] - bm[o] * sc;
    __syncthreads();
    #pragma unroll
    for (int it = 0; it < 16; ++it) {      // coalesced read, BN, LDS store
        int sl = it * 4 + (tid >> 6);
        int s2 = pp[sl];
        tile[sl * 65 + o] = (s2 >= 0)
            ? fmaxf(fmaf(acc5[(size_t)s2 * 64 + o], sc, sh), 0.f) : 0.f;
    }
    __syncthreads();
    #pragma unroll
    for (int it = 0; it < 16; ++it) {      // transposed dense write
        int og = it * 4 + (tid >> 6);
        int sl = tid & 63;
        int site = sb + sl;
        int d2 = site / HWC, yx = site - d2 * HWC;
        out[(size_t)(og * ND2 + d2) * HWC + yx] = tile[sl * 65 + og];
    }
}

// ---------------- launch ----------------
extern "C" void kernel_launch(void* const* d_in, const int* in_sizes, int n_in,
                              void* d_out, int out_size, void* d_ws, size_t ws_size,
                              hipStream_t stream) {
    const float* vf = (const float*)d_in[0];
    const float* w1 = (const float*)d_in[1];
    const float* w2 = (const float*)d_in[2];
    const float* w3 = (const float*)d_in[3];
    const float* w4 = (const float*)d_in[4];
    const float* w5 = (const float*)d_in[5];
    const float* bg = (const float*)d_in[6];
    const float* bb = (const float*)d_in[7];
    const float* bm = (const float*)d_in[8];
    const float* bv = (const float*)d_in[9];
    const int* coors = (const int*)d_in[10];
    float* out = (float*)d_out;

    char* ws = (char*)d_ws;
    size_t off = 0;
    auto take = [&](size_t n) -> void* {
        void* pp = ws + off;
        off += (n + 255) & ~(size_t)255;
        return pp;
    };
    // zero region: ctr + acc1 + accX + acc5 (one memset)
    int*   ctr  = (int*)take(16384);
    float* acc1 = (float*)take((size_t)NV * 64 * 4);
    float* accX = (float*)take((size_t)CAPN * 64 * 4);
    float* acc5 = (float*)take((size_t)CAPN * 64 * 4);
    size_t zero_len = (char*)acc5 + (size_t)CAPN * 64 * 4 - (char*)ctr;
    // 0xFF region: grid0 + grid1 + grid2 (one memset)
    int*   grid0 = (int*)take((size_t)D0 * HWC * 4);
    int*   grid1 = (int*)take((size_t)ND1 * HWC * 4);
    int*   grid2 = (int*)take((size_t)ND2 * HWC * 4);
    size_t ff_len = (char*)grid2 + (size_t)ND2 * HWC * 4 - (char*)grid0;
    int*   list1 = (int*)take(CAPN * 4);
    int*   list2 = (int*)take(CAPN * 4);
    float* w1t = (float*)take((size_t)27 * 128 * 64 * 4);
    float* w2t = (float*)take((size_t)3 * 64 * 64 * 4);
    float* w3t = (float*)take((size_t)27 * 64 * 64 * 4);
    float* w4t = (float*)take((size_t)27 * 64 * 64 * 4);
    float* w5t = (float*)take((size_t)3 * 64 * 64 * 4);
    float* fA  = (float*)take((size_t)NV * 64 * 4);
    float* fB  = (float*)take((size_t)CAPN * 64 * 4);
    int2*  pairs1  = (int2*)take((size_t)27 * NV * 8);     // strided NV
    int2*  pairs2  = (int2*)take((size_t)3 * CAPN * 8);    // strided CAPN
    int2*  pairs34 = (int2*)take((size_t)27 * CAPN * 8);
    int2*  pairs5  = (int2*)take((size_t)3 * CAPN * 8);

    hipMemsetAsync(ctr, 0x00, zero_len, stream);
    hipMemsetAsync(grid0, 0xFF, ff_len, stream);

    setup1_k<<<dim3(864, 6), 256, 0, stream>>>(coors, grid0, w1, w2, w3, w4, w5,
                                               w1t, w2t, w3t, w4t, w5t);
    setup2_k<<<2651, 256, 0, stream>>>(coors, grid0, grid1, grid2,
                                       list1, list2, ctr, pairs1);
    setup3_k<<<4125, 256, 0, stream>>>(grid0, grid1, list1, list2, ctr,
                                       pairs2, pairs34, pairs5);

    // conv1: 128->64, 27 taps, 8 quarter-waves per pair
    pconv_k<128, 8, 27, 8192, NV><<<1024, 256, 0, stream>>>(
        vf, w1t, pairs1, ctr + PC(2), acc1);
    bn_k<false, true><<<(NV * 64) / 256, 256, 0, stream>>>(acc1, fA, ctr,
        bg, bb, bm, bv);
    // conv2
    pconv_k<64, 4, 3, 4096, CAPN><<<1024, 256, 0, stream>>>(
        fA, w2t, pairs2, ctr + PC(29), accX);
    bn_k<true, false><<<(CAPN * 64) / 256, 256, 0, stream>>>(accX, fB, ctr,
        bg + 64, bb + 64, bm + 64, bv + 64);
    // conv3
    pconv_k<64, 4, 27, 4096, CAPN><<<1024, 256, 0, stream>>>(
        fB, w3t, pairs34, ctr + PC(32), accX);
    bn_k<true, false><<<(CAPN * 64) / 256, 256, 0, stream>>>(accX, fB, ctr,
        bg + 128, bb + 128, bm + 128, bv + 128);
    // conv4
    pconv_k<64, 4, 27, 4096, CAPN><<<1024, 256, 0, stream>>>(
        fB, w4t, pairs34, ctr + PC(32), accX);
    bn_k<false, false><<<(CAPN * 64) / 256, 256, 0, stream>>>(accX, fB, ctr,
        bg + 192, bb + 192, bm + 192, bv + 192);
    // conv5
    pconv_k<64, 4, 3, 4096, CAPN><<<1024, 256, 0, stream>>>(
        fB, w5t, pairs5, ctr + PC(59), acc5);
    // final BN + dense write (includes zeros -> no out memset needed)
    bn5_k<<<(ND2 * HWC) / 64, 256, 0, stream>>>(acc5, grid2,
        bg + 256, bb + 256, bm + 256, bv + 256, out);
}